// Round 9
// baseline (460.429 us; speedup 1.0000x reference)
//
#include <hip/hip_runtime.h>
#include <hip/hip_bf16.h>
#include <stdint.h>

#define NN 8192
#define DD 128
#define MAXDEG 128

typedef float f32x4 __attribute__((ext_vector_type(4)));
typedef unsigned int u32x4 __attribute__((ext_vector_type(4)));
typedef __bf16 bf16x8 __attribute__((ext_vector_type(8)));
typedef __bf16 bf16x4 __attribute__((ext_vector_type(4)));

__device__ __forceinline__ f32x4 mfma16(bf16x8 a, bf16x8 b, f32x4 c) {
    return __builtin_amdgcn_mfma_f32_16x16x32_bf16(a, b, c, 0, 0, 0);
}

__device__ __forceinline__ bf16x8 pack8(f32x4 lo, f32x4 hi) {
    bf16x8 r;
    r[0] = (__bf16)lo[0]; r[1] = (__bf16)lo[1]; r[2] = (__bf16)lo[2]; r[3] = (__bf16)lo[3];
    r[4] = (__bf16)hi[0]; r[5] = (__bf16)hi[1]; r[6] = (__bf16)hi[2]; r[7] = (__bf16)hi[3];
    return r;
}

__device__ __forceinline__ float fast_sigmoid(float x) {
    return __builtin_amdgcn_rcpf(1.0f + __expf(-x));
}

__device__ __forceinline__ uint32_t f32_bf16bits_rne(float f) {
    union { float f; uint32_t u; } c; c.f = f;
    return (c.u + 0x7fffu + ((c.u >> 16) & 1u)) >> 16;
}

__device__ __forceinline__ float bf16bits_f32(uint32_t b) {
    union { uint32_t u; float f; } c; c.u = b << 16;
    return c.f;
}

// ---------------- kernel 1: E = exp(Z @ w_V)  +  W -> bf16 convert (first 64 blocks) ----
__global__ __launch_bounds__(256) void k_prepA(
    const float* __restrict__ Z, const float* __restrict__ wV,
    const float* __restrict__ W_D, const float* __restrict__ W_C,
    const float* __restrict__ W1, const float* __restrict__ W2,
    float* __restrict__ E, __bf16* __restrict__ Wb)
{
    const int wid  = threadIdx.x >> 6;
    const int lane = threadIdx.x & 63;
    const int row  = blockIdx.x * 4 + wid;
    float p = Z[row * DD + lane] * wV[lane] + Z[row * DD + 64 + lane] * wV[64 + lane];
    #pragma unroll
    for (int off = 32; off > 0; off >>= 1) p += __shfl_xor(p, off, 64);
    if (lane == 0) E[row] = __expf(p);

    const int t = blockIdx.x * 256 + threadIdx.x;    // W convert: t in 0..16383
    if (t < 16384) {
        const int m = t >> 12, i = t & 4095;
        const float* src = (m == 0) ? W_D : (m == 1) ? W_C : (m == 2) ? W1 : W2;
        const f32x4 v = *(const f32x4*)(src + i * 4);
        bf16x4 b;
        b[0] = (__bf16)v[0]; b[1] = (__bf16)v[1]; b[2] = (__bf16)v[2]; b[3] = (__bf16)v[3];
        *(bf16x4*)(Wb + m * 16384 + i * 4) = b;
    }
}

// ---------------- kernel 2: XR (bf16 row-major), YB (blocked), REA (bf16 row-major) ----
// YB blocked layout: element (k, col) at (k>>5)*4096 + col*32 + (k&31).
__global__ __launch_bounds__(256) void k_prep2(
    const float* __restrict__ Z, const __bf16* __restrict__ Wb,
    const float* __restrict__ b1, const float* __restrict__ b2,
    const float* __restrict__ delta_logit,
    __bf16* __restrict__ XR, __bf16* __restrict__ YB, __bf16* __restrict__ REA)
{
    __shared__ __bf16 Hs[32][136];
    const int tid = threadIdx.x;
    const int w = tid >> 6, l = tid & 63;
    const int lr = l & 15, lg = l >> 4;
    const int wr = w & 1, wn = w >> 1;
    const int r0 = blockIdx.x * 32;
    const int arow = r0 + 16 * wr + lr;
    const __bf16* WDb = Wb;
    const __bf16* WCb = Wb + 16384;
    const __bf16* W1b = Wb + 32768;
    const __bf16* W2b = Wb + 49152;

    const f32x4 zero4 = {0.f, 0.f, 0.f, 0.f};
    f32x4 aXD[4], aY[4], aH[4];
    #pragma unroll
    for (int i = 0; i < 4; ++i) { aXD[i] = zero4; aY[i] = zero4; aH[i] = zero4; }

    #pragma unroll
    for (int t = 0; t < 4; ++t) {
        const int k0 = 32 * t + 8 * lg;
        const bf16x8 af = pack8(*(const f32x4*)(Z + arow * DD + k0),
                                *(const f32x4*)(Z + arow * DD + k0 + 4));
        #pragma unroll
        for (int nf = 0; nf < 4; ++nf) {
            const int col = 64 * wn + 16 * nf + lr;
            aXD[nf] = mfma16(af, *(const bf16x8*)(WDb + col * DD + k0), aXD[nf]);
            aY[nf]  = mfma16(af, *(const bf16x8*)(WCb + col * DD + k0), aY[nf]);
            aH[nf]  = mfma16(af, *(const bf16x8*)(W1b + col * DD + k0), aH[nf]);
        }
    }

    const int orow = r0 + 16 * wr + 4 * lg;     // output row base (rows orow..orow+3)
    const int tile = orow >> 5;
    #pragma unroll
    for (int nf = 0; nf < 4; ++nf) {
        const int col = 64 * wn + 16 * nf + lr;
        bf16x4 yo;
        const float bb1 = b1[col];
        #pragma unroll
        for (int r = 0; r < 4; ++r) {
            XR[(orow + r) * DD + col] = (__bf16)aXD[nf][r];
            yo[r] = (__bf16)aY[nf][r];
            const float x = aH[nf][r] + bb1;
            const float e = __expf(2.0f * x);
            Hs[16 * wr + 4 * lg + r][col] = (__bf16)(1.0f - 2.0f * __builtin_amdgcn_rcpf(e + 1.0f));
        }
        *(bf16x4*)(YB + tile * 4096 + col * 32 + (orow & 31)) = yo;
    }
    __syncthreads();

    f32x4 aR[4];
    #pragma unroll
    for (int i = 0; i < 4; ++i) aR[i] = zero4;
    #pragma unroll
    for (int t = 0; t < 4; ++t) {
        const int k0 = 32 * t + 8 * lg;
        const bf16x8 hf = *(const bf16x8*)(&Hs[16 * wr + lr][k0]);
        #pragma unroll
        for (int nf = 0; nf < 4; ++nf) {
            const int col = 64 * wn + 16 * nf + lr;
            aR[nf] = mfma16(hf, *(const bf16x8*)(W2b + col * DD + k0), aR[nf]);
        }
    }
    const float delta = fast_sigmoid(delta_logit[0]);
    #pragma unroll
    for (int nf = 0; nf < 4; ++nf) {
        const int col = 64 * wn + 16 * nf + lr;
        const float bb2 = b2[col];
        #pragma unroll
        for (int r = 0; r < 4; ++r)
            REA[(orow + r) * DD + col] = (__bf16)(delta * (aR[nf][r] + bb2));
    }
}

// ---------------- kernel 3: fused A-scan (LDS buckets) + con MFMA + dif gather ----------
// grid 256 (32 rows each), 512 threads = 8 waves.
// Phase 0: each wave scans 4 rows of A (coalesced 1KB/instr) -> LDS buckets, atomic-free.
// Phase 1: con = softmax(g) @ Y via MFMA, kh8 K-split + LDS tree reduce.
// Phase 2: dif gather from LDS buckets + epilogue.
__global__ __launch_bounds__(512) __attribute__((amdgpu_waves_per_eu(2, 2))) void k_main(
    const float* __restrict__ A, const float* __restrict__ E,
    const __bf16* __restrict__ YB, const __bf16* __restrict__ XR,
    const __bf16* __restrict__ REA, const float* __restrict__ omega_logit,
    float* __restrict__ out)
{
    __shared__ float red[4][64][76];          // 76KB tree-reduce buffers
    __shared__ uint32_t ents_lds[32][MAXDEG]; // 16KB per-row (col,val) buckets
    __shared__ uint32_t cnt_lds[32];
    float* conS = &red[0][0][0];              // overlay after reduce: [32][132] + den[32]
    const int tid = threadIdx.x;
    const int w = tid >> 6, l = tid & 63;
    const int lr = l & 15, lg = l >> 4;
    const int r0 = blockIdx.x * 32;

    // ---- phase 0: scan this block's 32 rows of A ----
    for (int j = 0; j < 4; ++j) {
        const int rrow = 4 * w + j;           // 0..31
        const float* rp = A + (size_t)(r0 + rrow) * NN + l * 4;
        uint32_t* eb = &ents_lds[rrow][0];
        uint32_t base = 0;
        #pragma unroll 4
        for (int i = 0; i < 32; ++i) {
            const f32x4 v = *(const f32x4*)(rp + i * 256);
            const int colb = i * 256 + l * 4;
            #pragma unroll
            for (int k = 0; k < 4; ++k) {
                const bool nz = (v[k] != 0.0f);
                const unsigned long long m = __ballot(nz);
                if (nz) {
                    const uint32_t pfx = __builtin_amdgcn_mbcnt_hi(
                        (uint32_t)(m >> 32), __builtin_amdgcn_mbcnt_lo((uint32_t)m, 0u));
                    const uint32_t slot = base + pfx;
                    if (slot < MAXDEG)
                        eb[slot] = ((uint32_t)(colb + k) << 16) | f32_bf16bits_rne(v[k]);
                }
                base += (uint32_t)__popcll(m);
            }
        }
        if (l == 0) cnt_lds[rrow] = min(base, (uint32_t)MAXDEG);
    }
    __syncthreads();

    // ---- phase 1: con MFMA, kh8 K-split (wave: 32 rows x 128 cols, K=1024) ----
    const int kstart = w * 1024;
    const float* ep = E + kstart + 8 * lg;
    const __bf16* yp = YB + (kstart >> 5) * 4096 + lr * 32 + 8 * lg;
    const float u0 = E[r0 + lr];
    const float u1 = E[r0 + 16 + lr];

    const f32x4 zero4 = {0.f, 0.f, 0.f, 0.f};
    f32x4 aC0[8], aC1[8], aden0 = zero4, aden1 = zero4;
    #pragma unroll
    for (int i = 0; i < 8; ++i) { aC0[i] = zero4; aC1[i] = zero4; }
    bf16x8 ones;
    #pragma unroll
    for (int i = 0; i < 8; ++i) ones[i] = (__bf16)1.0f;

    f32x4 eAa, eBa, eAb, eBb;
    bf16x8 bya[8], byb[8];
    intptr_t adv = 32;

#define LOADT(S) do {                                                         \
        eA##S = *(const f32x4*)(ep); eB##S = *(const f32x4*)(ep + 4);         \
        _Pragma("unroll")                                                     \
        for (int c = 0; c < 8; ++c) by##S[c] = *(const bf16x8*)(yp + c * 512);\
        ep += adv; yp += adv * 128;                                           \
    } while (0)

#define COMPT(S) do {                                                         \
        bf16x8 gf0, gf1;                                                      \
        _Pragma("unroll")                                                     \
        for (int j = 0; j < 4; ++j) {                                         \
            const float ea = eA##S[j], eb = eB##S[j];                         \
            gf0[j]     = (__bf16)__expf(u0 * __builtin_amdgcn_rcpf(u0 + ea)); \
            gf0[4 + j] = (__bf16)__expf(u0 * __builtin_amdgcn_rcpf(u0 + eb)); \
            gf1[j]     = (__bf16)__expf(u1 * __builtin_amdgcn_rcpf(u1 + ea)); \
            gf1[4 + j] = (__bf16)__expf(u1 * __builtin_amdgcn_rcpf(u1 + eb)); \
        }                                                                     \
        _Pragma("unroll")                                                     \
        for (int c = 0; c < 8; ++c) {                                         \
            aC0[c] = mfma16(gf0, by##S[c], aC0[c]);                           \
            aC1[c] = mfma16(gf1, by##S[c], aC1[c]);                           \
        }                                                                     \
        aden0 = mfma16(gf0, ones, aden0);                                     \
        aden1 = mfma16(gf1, ones, aden1);                                     \
    } while (0)

    LOADT(a);                              // tile 0
    for (int it = 0; it < 16; ++it) {      // 32 tiles total
        if (it == 15) adv = 0;
        LOADT(b); COMPT(a);
        LOADT(a); COMPT(b);
    }
#undef LOADT
#undef COMPT

#define STORE_ACC(dst) do {                                                   \
        _Pragma("unroll")                                                     \
        for (int c = 0; c < 8; ++c) {                                         \
            *(f32x4*)((dst) + c * 4)      = aC0[c];                           \
            *(f32x4*)((dst) + 36 + c * 4) = aC1[c];                           \
        }                                                                     \
        *(f32x4*)((dst) + 32)      = aden0;                                   \
        *(f32x4*)((dst) + 36 + 32) = aden1;                                   \
    } while (0)
#define ADD_ACC(src) do {                                                     \
        _Pragma("unroll")                                                     \
        for (int c = 0; c < 8; ++c) {                                         \
            aC0[c] += *(const f32x4*)((src) + c * 4);                         \
            aC1[c] += *(const f32x4*)((src) + 36 + c * 4);                    \
        }                                                                     \
        aden0 += *(const f32x4*)((src) + 32);                                 \
        aden1 += *(const f32x4*)((src) + 36 + 32);                            \
    } while (0)

    // tree reduce: 8 -> 4 -> 2 -> 1 (into wave 0)
    if (w >= 4) STORE_ACC(&red[w - 4][l][0]);
    __syncthreads();
    if (w < 4) ADD_ACC(&red[w][l][0]);
    __syncthreads();
    if (w == 2 || w == 3) STORE_ACC(&red[w - 2][l][0]);
    __syncthreads();
    if (w < 2) ADD_ACC(&red[w][l][0]);
    __syncthreads();
    if (w == 1) STORE_ACC(&red[0][l][0]);
    __syncthreads();
    if (w == 0) {
        ADD_ACC(&red[0][l][0]);
        __builtin_amdgcn_s_barrier();       // all other waves already at barrier below
        // write con numerator + denominator to LDS overlay
        #pragma unroll
        for (int rf = 0; rf < 2; ++rf) {
            #pragma unroll
            for (int c = 0; c < 8; ++c) {
                const f32x4 v = rf ? aC1[c] : aC0[c];
                #pragma unroll
                for (int r = 0; r < 4; ++r)
                    conS[(16 * rf + 4 * lg + r) * 132 + 16 * c + lr] = v[r];
            }
            if (lr == 0) {
                const f32x4 d = rf ? aden1 : aden0;
                #pragma unroll
                for (int r = 0; r < 4; ++r)
                    conS[32 * 132 + 16 * rf + 4 * lg + r] = d[r];
            }
        }
    } else {
        __builtin_amdgcn_s_barrier();       // matches wave0's explicit barrier
    }
    __syncthreads();

    // ---- phase 2: dif gather from LDS buckets (4-deep) + combine ----
    const int row = tid >> 4;               // 0..31
    const int g16 = tid & 15;
    const int col0 = 8 * g16;
    const int rg = r0 + row;
    float acc[8];
    #pragma unroll
    for (int i = 0; i < 8; ++i) acc[i] = 0.0f;

    const uint32_t n = cnt_lds[row];
    const uint32_t* ep2 = &ents_lds[row][0];
    uint32_t e = 0;
    for (; e + 4 <= n; e += 4) {
        const u32x4 p = *(const u32x4*)(ep2 + e);
        const bf16x8 x0 = *(const bf16x8*)(XR + (size_t)(p[0] >> 16) * DD + col0);
        const bf16x8 x1 = *(const bf16x8*)(XR + (size_t)(p[1] >> 16) * DD + col0);
        const bf16x8 x2 = *(const bf16x8*)(XR + (size_t)(p[2] >> 16) * DD + col0);
        const bf16x8 x3 = *(const bf16x8*)(XR + (size_t)(p[3] >> 16) * DD + col0);
        const float v0 = bf16bits_f32(p[0] & 0xffffu);
        const float v1 = bf16bits_f32(p[1] & 0xffffu);
        const float v2 = bf16bits_f32(p[2] & 0xffffu);
        const float v3 = bf16bits_f32(p[3] & 0xffffu);
        #pragma unroll
        for (int i = 0; i < 8; ++i)
            acc[i] += v0 * (float)x0[i] + v1 * (float)x1[i]
                    + v2 * (float)x2[i] + v3 * (float)x3[i];
    }
    for (; e < n; ++e) {
        const uint32_t p = ep2[e];
        const float val = bf16bits_f32(p & 0xffffu);
        const bf16x8 xv = *(const bf16x8*)(XR + (size_t)(p >> 16) * DD + col0);
        #pragma unroll
        for (int i = 0; i < 8; ++i) acc[i] += val * (float)xv[i];
    }

    const float omega = fast_sigmoid(omega_logit[0]);
    const float om1 = 1.0f - omega;
    const float dinv = __builtin_amdgcn_rcpf(conS[32 * 132 + row]);
    const bf16x8 rea8 = *(const bf16x8*)(REA + (size_t)rg * DD + col0);
    f32x4 o0, o1;
    #pragma unroll
    for (int i = 0; i < 8; ++i) {
        const float dv = fmaxf(acc[i], 0.0f);
        const float cv = conS[row * 132 + col0 + i] * dinv;
        const float v = (float)rea8[i] + omega * dv + om1 * cv;
        if (i < 4) o0[i] = v; else o1[i - 4] = v;
    }
    *(f32x4*)(out + (size_t)rg * DD + col0) = o0;
    *(f32x4*)(out + (size_t)rg * DD + col0 + 4) = o1;
}

extern "C" void kernel_launch(void* const* d_in, const int* in_sizes, int n_in,
                              void* d_out, int out_size, void* d_ws, size_t ws_size,
                              hipStream_t stream) {
    (void)in_sizes; (void)n_in; (void)out_size; (void)ws_size;
    const float* Z   = (const float*)d_in[0];
    const float* A   = (const float*)d_in[1];
    const float* W_D = (const float*)d_in[2];
    const float* W_C = (const float*)d_in[3];
    const float* wV  = (const float*)d_in[4];
    const float* W1  = (const float*)d_in[5];
    const float* b1  = (const float*)d_in[6];
    const float* W2  = (const float*)d_in[7];
    const float* b2  = (const float*)d_in[8];
    const float* omega_logit = (const float*)d_in[9];
    const float* delta_logit = (const float*)d_in[10];
    float* out = (float*)d_out;

    // ws layout (bytes): E 32K | Wb 128K | XR 2M | YB 2M | REA 2M  (~6.3MB)
    char* wsb = (char*)d_ws;
    float*  E   = (float*)wsb;
    __bf16* Wb  = (__bf16*)(wsb + 32768);
    __bf16* XR  = (__bf16*)(wsb + 163840);
    __bf16* YB  = (__bf16*)(wsb + 163840 + 2097152);
    __bf16* REA = (__bf16*)(wsb + 163840 + 2 * 2097152);

    k_prepA<<<dim3(2048), dim3(256), 0, stream>>>(Z, wV, W_D, W_C, W1, W2, E, Wb);
    k_prep2<<<dim3(256), dim3(256), 0, stream>>>(Z, Wb, b1, b2, delta_logit, XR, YB, REA);
    k_main<<<dim3(256), dim3(512), 0, stream>>>(A, E, YB, XR, REA, omega_logit, out);
}

// Round 11
// 437.097 us; speedup vs baseline: 1.0534x; 1.0534x over previous
//
#include <hip/hip_runtime.h>
#include <hip/hip_bf16.h>
#include <stdint.h>

#define NN 8192
#define DD 128
#define CAP 160

typedef float f32x4 __attribute__((ext_vector_type(4)));
typedef unsigned int u32x4 __attribute__((ext_vector_type(4)));
typedef unsigned short u16x4 __attribute__((ext_vector_type(4)));
typedef __bf16 bf16x8 __attribute__((ext_vector_type(8)));
typedef __bf16 bf16x4 __attribute__((ext_vector_type(4)));

__device__ __forceinline__ f32x4 mfma16(bf16x8 a, bf16x8 b, f32x4 c) {
    return __builtin_amdgcn_mfma_f32_16x16x32_bf16(a, b, c, 0, 0, 0);
}

__device__ __forceinline__ bf16x8 pack8(f32x4 lo, f32x4 hi) {
    bf16x8 r;
    r[0] = (__bf16)lo[0]; r[1] = (__bf16)lo[1]; r[2] = (__bf16)lo[2]; r[3] = (__bf16)lo[3];
    r[4] = (__bf16)hi[0]; r[5] = (__bf16)hi[1]; r[6] = (__bf16)hi[2]; r[7] = (__bf16)hi[3];
    return r;
}

__device__ __forceinline__ float fast_sigmoid(float x) {
    return __builtin_amdgcn_rcpf(1.0f + __expf(-x));
}

// ---------------- kernel 1: A -> bitmask + dsq, E = exp(Z@w_V), W -> bf16 --------------
// grid 2048 x 256 (4 waves). Wave w scans row = bid*4+w: pure per-lane stream, NO
// cross-lane ops in the loop. Lane-permuted mask layout (decoded in k_main):
// word[g*64+l] bit (t*4+r) = A[row][(g*8+t)*256 + l*4 + r] != 0.
__global__ __launch_bounds__(256) void k_scan2(
    const float* __restrict__ A, const float* __restrict__ Z,
    const float* __restrict__ wV, const float* __restrict__ W_D,
    const float* __restrict__ W_C, const float* __restrict__ W1,
    const float* __restrict__ W2, uint32_t* __restrict__ mask,
    float* __restrict__ dsq, float* __restrict__ E, __bf16* __restrict__ Wb)
{
    const int w = threadIdx.x >> 6, l = threadIdx.x & 63;
    const int row = blockIdx.x * 4 + w;

    const float* rp = A + (size_t)row * NN + l * 4;
    uint32_t* mrow = mask + (size_t)row * 256;
    uint32_t dcnt = 0;
    #pragma unroll
    for (int g = 0; g < 4; ++g) {
        uint32_t mw = 0;
        #pragma unroll
        for (int t = 0; t < 8; ++t) {
            const f32x4 v = *(const f32x4*)(rp + (g * 8 + t) * 256);
            const uint32_t nb = (v[0] != 0.f ? 1u : 0u) | (v[1] != 0.f ? 2u : 0u)
                              | (v[2] != 0.f ? 4u : 0u) | (v[3] != 0.f ? 8u : 0u);
            mw |= nb << (t * 4);
        }
        mrow[g * 64 + l] = mw;
        dcnt += __popc(mw);
    }
    #pragma unroll
    for (int off = 32; off > 0; off >>= 1) dcnt += __shfl_xor((int)dcnt, off, 64);
    if (l == 0) dsq[row] = (dcnt > 0) ? 1.0f / sqrtf((float)dcnt) : 0.0f;

    // E = exp(Z @ w_V) for this row
    float p = Z[row * DD + l] * wV[l] + Z[row * DD + 64 + l] * wV[64 + l];
    #pragma unroll
    for (int off = 32; off > 0; off >>= 1) p += __shfl_xor(p, off, 64);
    if (l == 0) E[row] = __expf(p);

    // W convert (first 64 blocks' threads)
    const int t = blockIdx.x * 256 + threadIdx.x;
    if (t < 16384) {
        const int m = t >> 12, i = t & 4095;
        const float* src = (m == 0) ? W_D : (m == 1) ? W_C : (m == 2) ? W1 : W2;
        const f32x4 v = *(const f32x4*)(src + i * 4);
        bf16x4 b;
        b[0] = (__bf16)v[0]; b[1] = (__bf16)v[1]; b[2] = (__bf16)v[2]; b[3] = (__bf16)v[3];
        *(bf16x4*)(Wb + m * 16384 + i * 4) = b;
    }
}

// ---------------- kernel 2: XR (bf16, row j scaled by dsq[j]), YB (blocked), REA -------
// YB blocked layout: element (k, col) at (k>>5)*4096 + col*32 + (k&31).
__global__ __launch_bounds__(256) void k_prep2(
    const float* __restrict__ Z, const __bf16* __restrict__ Wb,
    const float* __restrict__ b1, const float* __restrict__ b2,
    const float* __restrict__ delta_logit, const float* __restrict__ dsq,
    __bf16* __restrict__ XR, __bf16* __restrict__ YB, __bf16* __restrict__ REA)
{
    __shared__ __bf16 Hs[32][136];
    const int tid = threadIdx.x;
    const int w = tid >> 6, l = tid & 63;
    const int lr = l & 15, lg = l >> 4;
    const int wr = w & 1, wn = w >> 1;
    const int r0 = blockIdx.x * 32;
    const int arow = r0 + 16 * wr + lr;
    const __bf16* WDb = Wb;
    const __bf16* WCb = Wb + 16384;
    const __bf16* W1b = Wb + 32768;
    const __bf16* W2b = Wb + 49152;

    const f32x4 zero4 = {0.f, 0.f, 0.f, 0.f};
    f32x4 aXD[4], aY[4], aH[4];
    #pragma unroll
    for (int i = 0; i < 4; ++i) { aXD[i] = zero4; aY[i] = zero4; aH[i] = zero4; }

    #pragma unroll
    for (int t = 0; t < 4; ++t) {
        const int k0 = 32 * t + 8 * lg;
        const bf16x8 af = pack8(*(const f32x4*)(Z + arow * DD + k0),
                                *(const f32x4*)(Z + arow * DD + k0 + 4));
        #pragma unroll
        for (int nf = 0; nf < 4; ++nf) {
            const int col = 64 * wn + 16 * nf + lr;
            aXD[nf] = mfma16(af, *(const bf16x8*)(WDb + col * DD + k0), aXD[nf]);
            aY[nf]  = mfma16(af, *(const bf16x8*)(WCb + col * DD + k0), aY[nf]);
            aH[nf]  = mfma16(af, *(const bf16x8*)(W1b + col * DD + k0), aH[nf]);
        }
    }

    const int orow = r0 + 16 * wr + 4 * lg;     // output row base (rows orow..orow+3)
    const int tile = orow >> 5;
    const f32x4 dsq4 = *(const f32x4*)(dsq + orow);
    #pragma unroll
    for (int nf = 0; nf < 4; ++nf) {
        const int col = 64 * wn + 16 * nf + lr;
        bf16x4 yo;
        const float bb1 = b1[col];
        #pragma unroll
        for (int r = 0; r < 4; ++r) {
            XR[(orow + r) * DD + col] = (__bf16)(aXD[nf][r] * dsq4[r]);
            yo[r] = (__bf16)aY[nf][r];
            const float x = aH[nf][r] + bb1;
            const float e = __expf(2.0f * x);
            Hs[16 * wr + 4 * lg + r][col] = (__bf16)(1.0f - 2.0f * __builtin_amdgcn_rcpf(e + 1.0f));
        }
        *(bf16x4*)(YB + tile * 4096 + col * 32 + (orow & 31)) = yo;
    }
    __syncthreads();

    f32x4 aR[4];
    #pragma unroll
    for (int i = 0; i < 4; ++i) aR[i] = zero4;
    #pragma unroll
    for (int t = 0; t < 4; ++t) {
        const int k0 = 32 * t + 8 * lg;
        const bf16x8 hf = *(const bf16x8*)(&Hs[16 * wr + lr][k0]);
        #pragma unroll
        for (int nf = 0; nf < 4; ++nf) {
            const int col = 64 * wn + 16 * nf + lr;
            aR[nf] = mfma16(hf, *(const bf16x8*)(W2b + col * DD + k0), aR[nf]);
        }
    }
    const float delta = fast_sigmoid(delta_logit[0]);
    #pragma unroll
    for (int nf = 0; nf < 4; ++nf) {
        const int col = 64 * wn + 16 * nf + lr;
        const float bb2 = b2[col];
        #pragma unroll
        for (int r = 0; r < 4; ++r)
            REA[(orow + r) * DD + col] = (__bf16)(delta * (aR[nf][r] + bb2));
    }
}

// ---------------- kernel 3: mask decode + con MFMA + dif gather + epilogue -------------
// grid 256 (32 rows each), 512 threads = 8 waves.
__global__ __launch_bounds__(512) __attribute__((amdgpu_waves_per_eu(2, 2))) void k_main(
    const uint32_t* __restrict__ mask, const float* __restrict__ E,
    const __bf16* __restrict__ YB, const __bf16* __restrict__ XR,
    const __bf16* __restrict__ REA, const float* __restrict__ dsq,
    const float* __restrict__ omega_logit, float* __restrict__ out)
{
    __shared__ float red[4][64][76];          // 76KB tree-reduce buffers
    __shared__ uint16_t ents16[32][CAP];      // 10KB per-row neighbor col lists
    __shared__ uint32_t cnt32[32];
    float* conS = &red[0][0][0];              // overlay after reduce: [32][132] + den[32]
    const int tid = threadIdx.x;
    const int w = tid >> 6, l = tid & 63;
    const int lr = l & 15, lg = l >> 4;
    const int r0 = blockIdx.x * 32;
    const int row = tid >> 4;                 // 0..31 (decode/gather role)
    const int g16 = tid & 15;

    // ---- phase 0: decode mask -> LDS col lists ----
    if (tid < 32) cnt32[tid] = 0;
    __syncthreads();
    {
        const uint32_t* mrow = mask + (size_t)(r0 + row) * 256 + g16 * 16;
        #pragma unroll
        for (int q = 0; q < 4; ++q) {
            const u32x4 mv = *(const u32x4*)(mrow + q * 4);
            #pragma unroll
            for (int s = 0; s < 4; ++s) {
                uint32_t m = mv[s];
                const int widx = g16 * 16 + q * 4 + s;
                const int cbase = (widx >> 6) * 8;
                const int coff = (widx & 63) * 4;
                while (m) {
                    const int b = __ffs(m) - 1; m &= m - 1;
                    const int col = (cbase + (b >> 2)) * 256 + coff + (b & 3);
                    const uint32_t slot = atomicAdd(&cnt32[row], 1u);
                    if (slot < CAP) ents16[row][slot] = (uint16_t)col;
                }
            }
        }
    }

    // ---- phase 1: con MFMA, kh8 K-split (wave: 32 rows x 128 cols, K=1024) ----
    const int kstart = w * 1024;
    const float* ep = E + kstart + 8 * lg;
    const __bf16* yp = YB + (kstart >> 5) * 4096 + lr * 32 + 8 * lg;
    const float u0 = E[r0 + lr];
    const float u1 = E[r0 + 16 + lr];

    const f32x4 zero4 = {0.f, 0.f, 0.f, 0.f};
    f32x4 aC0[8], aC1[8], aden0 = zero4, aden1 = zero4;
    #pragma unroll
    for (int i = 0; i < 8; ++i) { aC0[i] = zero4; aC1[i] = zero4; }
    bf16x8 ones;
    #pragma unroll
    for (int i = 0; i < 8; ++i) ones[i] = (__bf16)1.0f;

    f32x4 eAa, eBa, eAb, eBb;
    bf16x8 bya[8], byb[8];
    intptr_t adv = 32;

#define LOADT(S) do {                                                         \
        eA##S = *(const f32x4*)(ep); eB##S = *(const f32x4*)(ep + 4);         \
        _Pragma("unroll")                                                     \
        for (int c = 0; c < 8; ++c) by##S[c] = *(const bf16x8*)(yp + c * 512);\
        ep += adv; yp += adv * 128;                                           \
    } while (0)

#define COMPT(S) do {                                                         \
        bf16x8 gf0, gf1;                                                      \
        _Pragma("unroll")                                                     \
        for (int j = 0; j < 4; ++j) {                                         \
            const float ea = eA##S[j], eb = eB##S[j];                         \
            gf0[j]     = (__bf16)__expf(u0 * __builtin_amdgcn_rcpf(u0 + ea)); \
            gf0[4 + j] = (__bf16)__expf(u0 * __builtin_amdgcn_rcpf(u0 + eb)); \
            gf1[j]     = (__bf16)__expf(u1 * __builtin_amdgcn_rcpf(u1 + ea)); \
            gf1[4 + j] = (__bf16)__expf(u1 * __builtin_amdgcn_rcpf(u1 + eb)); \
        }                                                                     \
        _Pragma("unroll")                                                     \
        for (int c = 0; c < 8; ++c) {                                         \
            aC0[c] = mfma16(gf0, by##S[c], aC0[c]);                           \
            aC1[c] = mfma16(gf1, by##S[c], aC1[c]);                           \
        }                                                                     \
        aden0 = mfma16(gf0, ones, aden0);                                     \
        aden1 = mfma16(gf1, ones, aden1);                                     \
    } while (0)

    LOADT(a);                              // tile 0
    for (int it = 0; it < 16; ++it) {      // 32 tiles total
        if (it == 15) adv = 0;
        LOADT(b); COMPT(a);
        LOADT(a); COMPT(b);
    }
#undef LOADT
#undef COMPT

#define STORE_ACC(dst) do {                                                   \
        _Pragma("unroll")                                                     \
        for (int c = 0; c < 8; ++c) {                                         \
            *(f32x4*)((dst) + c * 4)      = aC0[c];                           \
            *(f32x4*)((dst) + 36 + c * 4) = aC1[c];                           \
        }                                                                     \
        *(f32x4*)((dst) + 32)      = aden0;                                   \
        *(f32x4*)((dst) + 36 + 32) = aden1;                                   \
    } while (0)
#define ADD_ACC(src) do {                                                     \
        _Pragma("unroll")                                                     \
        for (int c = 0; c < 8; ++c) {                                         \
            aC0[c] += *(const f32x4*)((src) + c * 4);                         \
            aC1[c] += *(const f32x4*)((src) + 36 + c * 4);                    \
        }                                                                     \
        aden0 += *(const f32x4*)((src) + 32);                                 \
        aden1 += *(const f32x4*)((src) + 36 + 32);                            \
    } while (0)

    // tree reduce: 8 -> 4 -> 2 -> 1 (into wave 0)
    __syncthreads();
    if (w >= 4) STORE_ACC(&red[w - 4][l][0]);
    __syncthreads();
    if (w < 4) ADD_ACC(&red[w][l][0]);
    __syncthreads();
    if (w == 2 || w == 3) STORE_ACC(&red[w - 2][l][0]);
    __syncthreads();
    if (w < 2) ADD_ACC(&red[w][l][0]);
    __syncthreads();
    if (w == 1) STORE_ACC(&red[0][l][0]);
    __syncthreads();
    if (w == 0) {
        ADD_ACC(&red[0][l][0]);
        __builtin_amdgcn_s_barrier();       // all other waves already at barrier below
        #pragma unroll
        for (int rf = 0; rf < 2; ++rf) {
            #pragma unroll
            for (int c = 0; c < 8; ++c) {
                const f32x4 v = rf ? aC1[c] : aC0[c];
                #pragma unroll
                for (int r = 0; r < 4; ++r)
                    conS[(16 * rf + 4 * lg + r) * 132 + 16 * c + lr] = v[r];
            }
            if (lr == 0) {
                const f32x4 d = rf ? aden1 : aden0;
                #pragma unroll
                for (int r = 0; r < 4; ++r)
                    conS[32 * 132 + 16 * rf + 4 * lg + r] = d[r];
            }
        }
    } else {
        __builtin_amdgcn_s_barrier();       // matches wave0's explicit barrier
    }
    __syncthreads();

    // ---- phase 2: dif gather from LDS col lists (4-deep) + combine ----
    const int col0 = 8 * g16;
    const int rg = r0 + row;
    float acc[8];
    #pragma unroll
    for (int i = 0; i < 8; ++i) acc[i] = 0.0f;

    const uint32_t n = min(cnt32[row], (uint32_t)CAP);
    uint32_t e = 0;
    for (; e + 4 <= n; e += 4) {
        const u16x4 p = *(const u16x4*)(&ents16[row][e]);
        const bf16x8 x0 = *(const bf16x8*)(XR + (size_t)p[0] * DD + col0);
        const bf16x8 x1 = *(const bf16x8*)(XR + (size_t)p[1] * DD + col0);
        const bf16x8 x2 = *(const bf16x8*)(XR + (size_t)p[2] * DD + col0);
        const bf16x8 x3 = *(const bf16x8*)(XR + (size_t)p[3] * DD + col0);
        #pragma unroll
        for (int i = 0; i < 8; ++i)
            acc[i] += (float)x0[i] + (float)x1[i] + (float)x2[i] + (float)x3[i];
    }
    for (; e < n; ++e) {
        const bf16x8 xv = *(const bf16x8*)(XR + (size_t)ents16[row][e] * DD + col0);
        #pragma unroll
        for (int i = 0; i < 8; ++i) acc[i] += (float)xv[i];
    }

    const float omega = fast_sigmoid(omega_logit[0]);
    const float om1 = 1.0f - omega;
    const float dsqi = dsq[rg];
    const float dinv = __builtin_amdgcn_rcpf(conS[32 * 132 + row]);
    const bf16x8 rea8 = *(const bf16x8*)(REA + (size_t)rg * DD + col0);
    f32x4 o0, o1;
    #pragma unroll
    for (int i = 0; i < 8; ++i) {
        const float dv = fmaxf(dsqi * acc[i], 0.0f);
        const float cv = conS[row * 132 + col0 + i] * dinv;
        const float v = (float)rea8[i] + omega * dv + om1 * cv;
        if (i < 4) o0[i] = v; else o1[i - 4] = v;
    }
    *(f32x4*)(out + (size_t)rg * DD + col0) = o0;
    *(f32x4*)(out + (size_t)rg * DD + col0 + 4) = o1;
}

extern "C" void kernel_launch(void* const* d_in, const int* in_sizes, int n_in,
                              void* d_out, int out_size, void* d_ws, size_t ws_size,
                              hipStream_t stream) {
    (void)in_sizes; (void)n_in; (void)out_size; (void)ws_size;
    const float* Z   = (const float*)d_in[0];
    const float* A   = (const float*)d_in[1];
    const float* W_D = (const float*)d_in[2];
    const float* W_C = (const float*)d_in[3];
    const float* wV  = (const float*)d_in[4];
    const float* W1  = (const float*)d_in[5];
    const float* b1  = (const float*)d_in[6];
    const float* W2  = (const float*)d_in[7];
    const float* b2  = (const float*)d_in[8];
    const float* omega_logit = (const float*)d_in[9];
    const float* delta_logit = (const float*)d_in[10];
    float* out = (float*)d_out;

    // ws layout (bytes): E 32K | Wb 128K | XR 2M | YB 2M | REA 2M | dsq 32K | mask 8M
    char* wsb = (char*)d_ws;
    float*    E    = (float*)wsb;
    __bf16*   Wb   = (__bf16*)(wsb + 32768);
    __bf16*   XR   = (__bf16*)(wsb + 163840);
    __bf16*   YB   = (__bf16*)(wsb + 163840 + 2097152);
    __bf16*   REA  = (__bf16*)(wsb + 163840 + 2 * 2097152);
    float*    dsq  = (float*)(wsb + 163840 + 3 * 2097152);
    uint32_t* mask = (uint32_t*)(wsb + 163840 + 3 * 2097152 + 32768);
    // total ~14.5 MB

    k_scan2<<<dim3(2048), dim3(256), 0, stream>>>(A, Z, wV, W_D, W_C, W1, W2,
                                                  mask, dsq, E, Wb);
    k_prep2<<<dim3(256), dim3(256), 0, stream>>>(Z, Wb, b1, b2, delta_logit, dsq,
                                                 XR, YB, REA);
    k_main<<<dim3(256), dim3(512), 0, stream>>>(mask, E, YB, XR, REA, dsq,
                                                omega_logit, out);
}